// Round 2
// baseline (190.392 us; speedup 1.0000x reference)
//
#include <hip/hip_runtime.h>

typedef unsigned int u32;
typedef unsigned long long u64;
typedef float v2f __attribute__((ext_vector_type(2)));

#define NBATCH 8
#define NPTS   4096
#define NQTOT  (NBATCH * NPTS)   /* 32768 */
#define KNN    16
#define NBASIS 8
#define OUTM   64
#define NSPLIT 16
#define WIN    (NPTS / NSPLIT)   /* 256 candidates per window */
#define QPB    64
#define TKNN   (QPB * NSPLIT)    /* 1024 threads = 16 waves */
#define GRP    8
#define BUFCAP 64
/* per-query LDS row: 64 funnel slots + 16 t16 slots + 1 pad (odd stride) */
#define ROWSTR 81
#define TOFF   64

// sentinel: d2 = +inf, idx = all-ones (sorts last)
#define SENT 0x7f800000ffffffffull

__device__ __forceinline__ void ce(u64& x, u64& y) {
  u64 a = x, b = y;
  bool sw = b < a;
  x = sw ? b : a;
  y = sw ? a : b;
}

// Batcher odd-even mergesort network (fully unrolled).
template <int N>
__device__ __forceinline__ void oems_sort(u64* a) {
#pragma unroll
  for (int p = 1; p < N; p <<= 1) {
#pragma unroll
    for (int k = p; k >= 1; k >>= 1) {
#pragma unroll
      for (int j = k & (p - 1); j + k < N; j += 2 * k) {
#pragma unroll
        for (int i = 0; i < k; ++i) {
          int lo = i + j, hi = i + j + k;
          if (hi < N && (lo / (2 * p)) == (hi / (2 * p)))
            ce(a[lo], a[hi]);
        }
      }
    }
  }
}

// t, a sorted asc -> t = smallest 16 of union, sorted asc.
__device__ __forceinline__ void merge16(u64 t[16], const u64 a[16]) {
  u64 m[16];
#pragma unroll
  for (int i = 0; i < 16; ++i) {
    u64 x = t[i], y = a[15 - i];
    m[i] = (x < y) ? x : y;
  }
#pragma unroll
  for (int k = 8; k >= 1; k >>= 1) {
#pragma unroll
    for (int i = 0; i < 16; ++i) {
      if ((i & k) == 0) ce(m[i], m[i | k]);
    }
  }
#pragma unroll
  for (int i = 0; i < 16; ++i) t[i] = m[i];
}

// Bit-exact d2 for a candidate pair: ((dx^2+dy^2)+dz^2), no FMA contraction.
// float2 ext-vector ops lower to v_pk_{add,mul}_f32 (IEEE-identical rounding;
// verified bit-exact vs reference). Each op reads at most ONE scalar-loaded
// operand (candidate) + VGPR (query) -> no v_mov SGPR-copy traffic. Round-1's
// fma(-X,qx,H) form read 2 SGPRs/op and regressed (VALUBusy 41->46).
__device__ __forceinline__ v2f d2pair(v2f cx, v2f cy, v2f cz, v2f qx, v2f qy,
                                      v2f qz) {
#pragma clang fp contract(off)
  v2f dx = cx - qx;
  v2f dy = cy - qy;
  v2f dz = cz - qz;
  v2f d2 = (dx * dx + dy * dy) + dz * dz;
  return d2;
}

// publish a sorted 16-list into funnel segment seg of this query's row
__device__ __forceinline__ void pub16(u64* row, int seg, const u64 s[16]) {
#pragma unroll
  for (int e = 0; e < 16; ++e) row[seg * 16 + e] = s[e];
}

// merge funnel segment seg into register list s
__device__ __forceinline__ void mrg16(const u64* row, int seg, u64 s[16]) {
  u64 a[16];
#pragma unroll
  for (int e = 0; e < 16; ++e) a[e] = row[seg * 16 + e];
  merge16(s, a);
}

// Fused kNN + tensor-product features, 16-wave occupancy version.
// Block = 64 queries x 16 disjoint windows (256 candidates each) = 1024 thr.
// Grid 512 blocks -> 2 blocks/CU -> 32 waves/CU (100% ceiling) vs round-0's
// 8-wave blocks (37%). Seed top-16 is built by a log-tree merge across waves
// (pairs -> quads -> octs -> final), reusing the 64-slot funnel; scan keeps
// round-0's exact packed-d2 path; digest wave rotates per phase. NO
// __launch_bounds__ min-waves: earlier rounds measured forced VGPR -> spills.
__global__ __launch_bounds__(TKNN) void se3_kernel(
    const float* __restrict__ Xp, const float* __restrict__ Yp,
    const float* __restrict__ Zp, const float4* __restrict__ cpad,
    const float* __restrict__ Wmat, float* __restrict__ out) {
  __shared__ u64 sBuf[QPB * ROWSTR];  // 41.5 KB: funnel + t16 per query row
  __shared__ u32 sCnt[QPB];
  __shared__ float sThr[QPB];
  __shared__ float sM[QPB * 25];      // reduced M[8][3], stride 25

  const int b = blockIdx.x;
  const int qg = blockIdx.y;
  const int tid = threadIdx.x;
  const int ql = tid & 63;
  const int sp = tid >> 6;  // window id, wave-uniform, 0..15
  const int qi = qg * QPB + ql;
  const int base = b * NPTS;

  if (tid < QPB) sCnt[tid] = 0;

  // per-lane query coords (coalesced)
  const float qx = Xp[base + qi];
  const float qy = Yp[base + qi];
  const float qz = Zp[base + qi];
  const v2f qxx = {qx, qx}, qyy = {qy, qy}, qzz = {qz, qz};

  // wave-uniform candidate window -> scalar loads feeding packed math
  const int wbase = __builtin_amdgcn_readfirstlane(sp * WIN);
  const v2f* xs2 = (const v2f*)(Xp + base + wbase);
  const v2f* ys2 = (const v2f*)(Yp + base + wbase);
  const v2f* zs2 = (const v2f*)(Zp + base + wbase);
  const int sj = qi - wbase;  // self position inside window (may be OOR)

  u64* row = sBuf + ql * ROWSTR;

  // ---- Seed: every wave sorts its window's first 16; log-tree merge ----
  {
    u64 s16[16];
    float cd[16];
#pragma unroll
    for (int p = 0; p < 8; ++p) {
      v2f d2 = d2pair(xs2[p], ys2[p], zs2[p], qxx, qyy, qzz);
      cd[2 * p + 0] = d2.x;
      cd[2 * p + 1] = d2.y;
    }
#pragma unroll
    for (int i = 0; i < 16; ++i) {
      u64 v = ((u64)__float_as_uint(cd[i]) << 32) | (u32)(wbase + i);
      s16[i] = (i == sj) ? SENT : v;
    }
    oems_sort<16>(s16);

    // tree merge: 16 lists -> 1, 64-slot funnel, alternating publish/merge.
    // R1: L8..L11 -> segs 0..3
    if (sp >= 8 && sp < 12) pub16(row, sp - 8, s16);
    __syncthreads();
    // waves 0..3 absorb: {w, w+8}
    if (sp < 4) mrg16(row, sp, s16);
    __syncthreads();
    // R2: L12..L15 -> segs 0..3
    if (sp >= 12) pub16(row, sp - 12, s16);
    __syncthreads();
    // waves 4..7 absorb: {w, w+8}
    if (sp >= 4 && sp < 8) mrg16(row, sp - 4, s16);
    __syncthreads();
    // R3: merged L4'..L7' -> segs 0..3
    if (sp >= 4 && sp < 8) pub16(row, sp - 4, s16);
    __syncthreads();
    // waves 0..3 absorb: quads {w, w+8, w+4, w+12}
    if (sp < 4) mrg16(row, sp, s16);
    __syncthreads();
    // R4: quads L2'', L3'' -> segs 0,1
    if (sp == 2 || sp == 3) pub16(row, sp - 2, s16);
    __syncthreads();
    // waves 0,1 absorb: octs
    if (sp < 2) mrg16(row, sp, s16);
    __syncthreads();
    // R5: oct L1''' -> seg 0
    if (sp == 1) pub16(row, 0, s16);
    __syncthreads();
    if (sp == 0) {
      mrg16(row, 0, s16);  // full 16-window top-16
#pragma unroll
      for (int e = 0; e < 16; ++e) row[TOFF + e] = s16[e];
      sThr[ql] = __uint_as_float((u32)(s16[15] >> 32));
    }
    __syncthreads();
  }
  float thr = sThr[ql];

  // self-exclusion mask precompute (avoids per-candidate j!=qi compare)
  const int selfgrp = (sj >= 0 && sj < WIN) ? (sj >> 3) : -1;
  const u32 selfbit = 1u << (sj & 7);

  // ---- Main scan: doubling phases; digest wave rotates (1..4) ----
#pragma unroll
  for (int ph = 0; ph < 4; ++ph) {
    const int cstart = 16 << ph;  // [16,32),[32,64),[64,128),[128,256)
    const int cend = 32 << ph;
    for (int g = cstart; g < cend; g += GRP) {
      v2f d2p[4];
#pragma unroll
      for (int p = 0; p < 4; ++p)
        d2p[p] = d2pair(xs2[(g >> 1) + p], ys2[(g >> 1) + p],
                        zs2[(g >> 1) + p], qxx, qyy, qzz);
      u32 want = 0;
#pragma unroll
      for (int i = 0; i < GRP; ++i)
        want |= (d2p[i >> 1][i & 1] <= thr) ? (1u << i) : 0u;
      if ((g >> 3) == selfgrp) want &= ~selfbit;
      if (__any(want)) {
#pragma unroll
        for (int i = 0; i < GRP; ++i) {
          if (want & (1u << i)) {
            u32 slot = atomicAdd(&sCnt[ql], 1u);
            if (slot < BUFCAP)
              sBuf[ql * ROWSTR + slot] =
                  ((u64)__float_as_uint(d2p[i >> 1][i & 1]) << 32) |
                  (u32)(wbase + g + i);
          }
        }
      }
    }
    __syncthreads();
    if (sp == ph + 1) {  // rotating digest wave (1..4)
      int n = (int)sCnt[ql];
      n = n < BUFCAP ? n : BUFCAP;
      if (__any(n > 0)) {
        u64 t16[16];
#pragma unroll
        for (int e = 0; e < 16; ++e) t16[e] = row[TOFF + e];
        for (int k = 0; __any(k < n); k += 16) {
          u64 a[16];
#pragma unroll
          for (int e = 0; e < 16; ++e)
            a[e] = (k + e < n) ? row[k + e] : SENT;
          oems_sort<16>(a);
          merge16(t16, a);
        }
#pragma unroll
        for (int e = 0; e < 16; ++e) row[TOFF + e] = t16[e];
        sThr[ql] = __uint_as_float((u32)(t16[15] >> 32));
      }
      sCnt[ql] = 0;
    }
    __syncthreads();
    thr = sThr[ql];
  }

  // ---- Epilogue phase 1 (waves 0-3): partial M over 4 neighbors each ----
  // Thread (q = tid&63, quarter k = sp) -> partials into dead funnel
  // floats [k*25, k*25+24) of row q (< float offset 100; sT starts at 128).
  if (sp < 4) {
    const int k = sp;
    u64 pv[4];
#pragma unroll
    for (int e = 0; e < 4; ++e)
      pv[e] = row[TOFF + k * 4 + e];
    float4 nc[4];
    float dd[4];
#pragma unroll
    for (int e = 0; e < 4; ++e) {
      nc[e] = cpad[base + (int)(u32)pv[e]];  // independent gathers
      dd[e] = __uint_as_float((u32)(pv[e] >> 32));
    }
    float M[24];
#pragma unroll
    for (int j = 0; j < 24; ++j) M[j] = 0.f;
#pragma unroll
    for (int e = 0; e < 4; ++e) {
      float rx = nc[e].x - qx;  // sender - receiver
      float ry = nc[e].y - qy;
      float rz = nc[e].z - qz;
      float dist = sqrtf(dd[e]);
      float inv = 1.0f / (dist + 1e-8f);
      rx *= inv; ry *= inv; rz *= inv;
      float cut = fminf(dist * 0.1f, 1.0f);
      float g[NBASIS], s = 0.f;
#pragma unroll
      for (int v = 0; v < NBASIS; ++v) {
        float t = cut - (float)v * (1.0f / 7.0f);
        g[v] = __expf(-32.0f * t * t);  // sigma = 1/8 -> 1/(2s^2) = 32
        s += g[v];
      }
      float rs = 1.0f / s;
#pragma unroll
      for (int v = 0; v < NBASIS; ++v) {
        float rb = g[v] * rs;
        M[v * 3 + 0] = fmaf(rb, rx, M[v * 3 + 0]);
        M[v * 3 + 1] = fmaf(rb, ry, M[v * 3 + 1]);
        M[v * 3 + 2] = fmaf(rb, rz, M[v * 3 + 2]);
      }
    }
    float* fp = (float*)row;
#pragma unroll
    for (int c = 0; c < 24; ++c) fp[k * 25 + c] = M[c];
  }
  __syncthreads();

  // ---- Reduce partials: thread (q = ql, comps sp*3..sp*3+2), sp<8 ----
  if (sp < 8) {
    const float* fp = (const float*)row;
#pragma unroll
    for (int j0 = 0; j0 < 3; ++j0) {
      int j = sp * 3 + j0;
      float s = fp[0 * 25 + j] + fp[1 * 25 + j] + fp[2 * 25 + j] +
                fp[3 * 25 + j];
      sM[ql * 25 + j] = s;
    }
  }
  __syncthreads();

  // ---- Epilogue phase 2 (all 16 waves): out[q][w*3+m], lane w = ql ----
  float wreg[NBASIS];
#pragma unroll
  for (int v = 0; v < NBASIS; ++v) wreg[v] = Wmat[v * OUTM + ql];
  const float scale = 0.022097086912079608f;  // (1/sqrt(8)) / 16
#pragma unroll
  for (int i = 0; i < 4; ++i) {
    int q = sp * 4 + i;  // wave-uniform -> sM broadcasts
    const float* mq = sM + q * 25;
    float a0 = 0.f, a1 = 0.f, a2 = 0.f;
#pragma unroll
    for (int v = 0; v < NBASIS; ++v) {
      a0 = fmaf(wreg[v], mq[v * 3 + 0], a0);
      a1 = fmaf(wreg[v], mq[v * 3 + 1], a1);
      a2 = fmaf(wreg[v], mq[v * 3 + 2], a2);
    }
    size_t o = (size_t)(base + qg * QPB + q) * (OUTM * 3) + ql * 3;
    out[o + 0] = a0 * scale;
    out[o + 1] = a1 * scale;
    out[o + 2] = a2 * scale;
  }
}

// coords [B*N][3] -> x/y/z planes + float4 array.
__global__ void prep_kernel(const float* __restrict__ coords,
                            float* __restrict__ Xp, float* __restrict__ Yp,
                            float* __restrict__ Zp, float4* __restrict__ cpad) {
  int i = blockIdx.x * 256 + threadIdx.x;
  if (i < NQTOT) {
    float x = coords[3 * i + 0];
    float y = coords[3 * i + 1];
    float z = coords[3 * i + 2];
    Xp[i] = x; Yp[i] = y; Zp[i] = z;
    cpad[i] = make_float4(x, y, z, 0.f);
  }
}

extern "C" void kernel_launch(void* const* d_in, const int* in_sizes, int n_in,
                              void* d_out, int out_size, void* d_ws, size_t ws_size,
                              hipStream_t stream) {
  const float* coords = (const float*)d_in[0];
  const float* Wmat = (const float*)d_in[1];
  float* out = (float*)d_out;

  char* w = (char*)d_ws;
  float* Xp = (float*)(w);               // 128 KB
  float* Yp = (float*)(w + 131072);
  float* Zp = (float*)(w + 262144);
  float4* cpad = (float4*)(w + 393216);  // 512 KB

  prep_kernel<<<dim3((NQTOT + 255) / 256), dim3(256), 0, stream>>>(coords, Xp, Yp, Zp, cpad);
  se3_kernel<<<dim3(NBATCH, NPTS / QPB), dim3(TKNN), 0, stream>>>(Xp, Yp, Zp, cpad, Wmat, out);
}

// Round 3
// 174.689 us; speedup vs baseline: 1.0899x; 1.0899x over previous
//
#include <hip/hip_runtime.h>

typedef unsigned int u32;
typedef unsigned long long u64;
typedef float v2f __attribute__((ext_vector_type(2)));

#define NBATCH 8
#define NPTS   4096
#define NQTOT  (NBATCH * NPTS)   /* 32768 */
#define KNN    16
#define NBASIS 8
#define OUTM   64
#define NSPLIT 8
#define WIN    (NPTS / NSPLIT)   /* 512 candidates per window */
#define QPB    64
#define TKNN   (QPB * NSPLIT)    /* 512 threads = 8 waves */
#define GRP    8
#define BUFCAP 64
/* per-query LDS row: 64 funnel slots + 16 t16 slots + 1 pad (odd stride) */
#define ROWSTR 81
#define TOFF   64

// sentinel: d2 = +inf, idx = all-ones (sorts last)
#define SENT 0x7f800000ffffffffull

__device__ __forceinline__ void ce(u64& x, u64& y) {
  u64 a = x, b = y;
  bool sw = b < a;
  x = sw ? b : a;
  y = sw ? a : b;
}

// Batcher odd-even mergesort network (fully unrolled).
template <int N>
__device__ __forceinline__ void oems_sort(u64* a) {
#pragma unroll
  for (int p = 1; p < N; p <<= 1) {
#pragma unroll
    for (int k = p; k >= 1; k >>= 1) {
#pragma unroll
      for (int j = k & (p - 1); j + k < N; j += 2 * k) {
#pragma unroll
        for (int i = 0; i < k; ++i) {
          int lo = i + j, hi = i + j + k;
          if (hi < N && (lo / (2 * p)) == (hi / (2 * p)))
            ce(a[lo], a[hi]);
        }
      }
    }
  }
}

// t, a sorted asc -> t = smallest 16 of union, sorted asc.
__device__ __forceinline__ void merge16(u64 t[16], const u64 a[16]) {
  u64 m[16];
#pragma unroll
  for (int i = 0; i < 16; ++i) {
    u64 x = t[i], y = a[15 - i];
    m[i] = (x < y) ? x : y;
  }
#pragma unroll
  for (int k = 8; k >= 1; k >>= 1) {
#pragma unroll
    for (int i = 0; i < 16; ++i) {
      if ((i & k) == 0) ce(m[i], m[i | k]);
    }
  }
#pragma unroll
  for (int i = 0; i < 16; ++i) t[i] = m[i];
}

// Bit-exact d2 for a candidate pair: ((dx^2+dy^2)+dz^2), no FMA contraction.
// float2 ext-vector ops lower to v_pk_{add,mul}_f32 (IEEE-identical rounding;
// verified bit-exact vs reference). Each op reads at most ONE scalar-loaded
// operand (candidate) + VGPR (query) -> no v_mov SGPR-copy traffic. Round-1's
// fma(-X,qx,H) form read 2 SGPRs/op and regressed (VALUBusy 41->46).
__device__ __forceinline__ v2f d2pair(v2f cx, v2f cy, v2f cz, v2f qx, v2f qy,
                                      v2f qz) {
#pragma clang fp contract(off)
  v2f dx = cx - qx;
  v2f dy = cy - qy;
  v2f dz = cz - qz;
  v2f d2 = (dx * dx + dy * dy) + dz * dz;
  return d2;
}

// Fused kNN + tensor-product features, de-serialized funnel version.
// Block = 64 queries x 8 disjoint windows (R0 structure — proven fastest;
// R2's 16-wave blocks raised occupancy 37->42 but regressed: barrier cost).
// Running top-16 per query lives in the query's LDS row (sT); phase digests
// rotate across waves; epilogue-M distributed over waves 0-3. Round-3 edit:
// insertion path pays ONE atomicAdd(popc(want)) per group (was one atomic +
// dependent LDS round-trip per candidate); slot = base + prefix-popcount.
// Same drop-at-64 semantics -> selection bit-identical. NO __launch_bounds__
// min-waves: earlier rounds measured forced VGPR -> scratch spills.
__global__ __launch_bounds__(TKNN) void se3_kernel(
    const float* __restrict__ Xp, const float* __restrict__ Yp,
    const float* __restrict__ Zp, const float4* __restrict__ cpad,
    const float* __restrict__ Wmat, float* __restrict__ out) {
  __shared__ u64 sBuf[QPB * ROWSTR];  // 41.5 KB: funnel + t16 per query row
  __shared__ u32 sCnt[QPB];
  __shared__ float sThr[QPB];
  __shared__ float sM[QPB * 25];      // reduced M[8][3], stride 25

  const int b = blockIdx.x;
  const int qg = blockIdx.y;
  const int tid = threadIdx.x;
  const int ql = tid & 63;
  const int sp = tid >> 6;  // window id, wave-uniform
  const int qi = qg * QPB + ql;
  const int base = b * NPTS;

  if (tid < QPB) sCnt[tid] = 0;

  // per-lane query coords (coalesced)
  const float qx = Xp[base + qi];
  const float qy = Yp[base + qi];
  const float qz = Zp[base + qi];
  const v2f qxx = {qx, qx}, qyy = {qy, qy}, qzz = {qz, qz};

  // wave-uniform candidate window -> scalar loads feeding packed math
  const int wbase = __builtin_amdgcn_readfirstlane(sp * WIN);
  const v2f* xs2 = (const v2f*)(Xp + base + wbase);
  const v2f* ys2 = (const v2f*)(Yp + base + wbase);
  const v2f* zs2 = (const v2f*)(Zp + base + wbase);
  const int sj = qi - wbase;  // self position inside window (may be OOR)

  // ---- Seed: every thread sorts its window's first 16 candidates ----
  {
    u64 s16[16];
    float cd[16];
#pragma unroll
    for (int p = 0; p < 8; ++p) {
      v2f d2 = d2pair(xs2[p], ys2[p], zs2[p], qxx, qyy, qzz);
      cd[2 * p + 0] = d2.x;
      cd[2 * p + 1] = d2.y;
    }
#pragma unroll
    for (int i = 0; i < 16; ++i) {
      u64 v = ((u64)__float_as_uint(cd[i]) << 32) | (u32)(wbase + i);
      s16[i] = (i == sj) ? SENT : v;
    }
    oems_sort<16>(s16);

    // Round A: waves 1..4 publish pre-sorted lists into funnel slots.
    if (sp >= 1 && sp <= 4) {
#pragma unroll
      for (int e = 0; e < 16; ++e)
        sBuf[ql * ROWSTR + (sp - 1) * 16 + e] = s16[e];
    }
    __syncthreads();
    if (sp == 0) {
      u64 t16[16];
#pragma unroll
      for (int e = 0; e < 16; ++e) t16[e] = s16[e];
#pragma unroll
      for (int s = 0; s < 4; ++s) {
        u64 a[16];
#pragma unroll
        for (int e = 0; e < 16; ++e) a[e] = sBuf[ql * ROWSTR + s * 16 + e];
        merge16(t16, a);
      }
      // stash partial in sT while round B publishes
#pragma unroll
      for (int e = 0; e < 16; ++e) sBuf[ql * ROWSTR + TOFF + e] = t16[e];
    }
    __syncthreads();
    // Round B: waves 5..7 publish.
    if (sp >= 5) {
#pragma unroll
      for (int e = 0; e < 16; ++e)
        sBuf[ql * ROWSTR + (sp - 5) * 16 + e] = s16[e];
    }
    __syncthreads();
    if (sp == 0) {
      u64 t16[16];
#pragma unroll
      for (int e = 0; e < 16; ++e) t16[e] = sBuf[ql * ROWSTR + TOFF + e];
#pragma unroll
      for (int s = 0; s < 3; ++s) {
        u64 a[16];
#pragma unroll
        for (int e = 0; e < 16; ++e) a[e] = sBuf[ql * ROWSTR + s * 16 + e];
        merge16(t16, a);
      }
#pragma unroll
      for (int e = 0; e < 16; ++e) sBuf[ql * ROWSTR + TOFF + e] = t16[e];
      sThr[ql] = __uint_as_float((u32)(t16[15] >> 32));
    }
    __syncthreads();
  }
  float thr = sThr[ql];

  // self-exclusion mask precompute (avoids per-candidate j!=qi compare)
  const int selfgrp = (sj >= 0 && sj < WIN) ? (sj >> 3) : -1;
  const u32 selfbit = 1u << (sj & 7);

  // ---- Main scan: doubling phases; digest wave rotates (1..5) ----
#pragma unroll
  for (int ph = 0; ph < 5; ++ph) {
    const int cstart = 16 << ph;  // [16,32),[32,64),...,[256,512)
    const int cend = 32 << ph;
#pragma unroll 2
    for (int g = cstart; g < cend; g += GRP) {
      v2f d2p[4];
#pragma unroll
      for (int p = 0; p < 4; ++p)
        d2p[p] = d2pair(xs2[(g >> 1) + p], ys2[(g >> 1) + p],
                        zs2[(g >> 1) + p], qxx, qyy, qzz);
      u32 want = 0;
#pragma unroll
      for (int i = 0; i < GRP; ++i)
        want |= (d2p[i >> 1][i & 1] <= thr) ? (1u << i) : 0u;
      if ((g >> 3) == selfgrp) want &= ~selfbit;
      if (__any(want)) {
        // ONE atomic per group: reserve popc(want) slots, then prefix-popc
        // assigns deterministic per-candidate slots (no per-insert LDS
        // round-trip dependency chain).
        u32 sbase = atomicAdd(&sCnt[ql], (u32)__popc(want));
#pragma unroll
        for (int i = 0; i < GRP; ++i) {
          if (want & (1u << i)) {
            u32 slot = sbase + (u32)__popc(want & ((1u << i) - 1u));
            if (slot < BUFCAP)
              sBuf[ql * ROWSTR + slot] =
                  ((u64)__float_as_uint(d2p[i >> 1][i & 1]) << 32) |
                  (u32)(wbase + g + i);
          }
        }
      }
    }
    __syncthreads();
    if (sp == ph + 1) {  // rotating digest wave (1..5)
      int n = (int)sCnt[ql];
      n = n < BUFCAP ? n : BUFCAP;
      if (__any(n > 0)) {
        u64 t16[16];
#pragma unroll
        for (int e = 0; e < 16; ++e) t16[e] = sBuf[ql * ROWSTR + TOFF + e];
        for (int k = 0; __any(k < n); k += 16) {
          u64 a[16];
#pragma unroll
          for (int e = 0; e < 16; ++e)
            a[e] = (k + e < n) ? sBuf[ql * ROWSTR + k + e] : SENT;
          oems_sort<16>(a);
          merge16(t16, a);
        }
#pragma unroll
        for (int e = 0; e < 16; ++e) sBuf[ql * ROWSTR + TOFF + e] = t16[e];
        sThr[ql] = __uint_as_float((u32)(t16[15] >> 32));
      }
      sCnt[ql] = 0;
    }
    __syncthreads();
    thr = sThr[ql];
  }

  // ---- Epilogue phase 1 (waves 0-3): partial M over 4 neighbors each ----
  // Thread (q = tid&63, quarter k = tid>>6) -> partials into dead funnel
  // floats [k*25, k*25+24) of row q (< float offset 100; sT starts at 128).
  if (sp < 4) {
    const int k = sp;
    u64 pv[4];
#pragma unroll
    for (int e = 0; e < 4; ++e)
      pv[e] = sBuf[ql * ROWSTR + TOFF + k * 4 + e];
    float4 nc[4];
    float dd[4];
#pragma unroll
    for (int e = 0; e < 4; ++e) {
      nc[e] = cpad[base + (int)(u32)pv[e]];  // independent gathers
      dd[e] = __uint_as_float((u32)(pv[e] >> 32));
    }
    float M[24];
#pragma unroll
    for (int j = 0; j < 24; ++j) M[j] = 0.f;
#pragma unroll
    for (int e = 0; e < 4; ++e) {
      float rx = nc[e].x - qx;  // sender - receiver
      float ry = nc[e].y - qy;
      float rz = nc[e].z - qz;
      float dist = sqrtf(dd[e]);
      float inv = 1.0f / (dist + 1e-8f);
      rx *= inv; ry *= inv; rz *= inv;
      float cut = fminf(dist * 0.1f, 1.0f);
      float g[NBASIS], s = 0.f;
#pragma unroll
      for (int v = 0; v < NBASIS; ++v) {
        float t = cut - (float)v * (1.0f / 7.0f);
        g[v] = __expf(-32.0f * t * t);  // sigma = 1/8 -> 1/(2s^2) = 32
        s += g[v];
      }
      float rs = 1.0f / s;
#pragma unroll
      for (int v = 0; v < NBASIS; ++v) {
        float rb = g[v] * rs;
        M[v * 3 + 0] = fmaf(rb, rx, M[v * 3 + 0]);
        M[v * 3 + 1] = fmaf(rb, ry, M[v * 3 + 1]);
        M[v * 3 + 2] = fmaf(rb, rz, M[v * 3 + 2]);
      }
    }
    float* fp = (float*)(sBuf + ql * ROWSTR);
#pragma unroll
    for (int c = 0; c < 24; ++c) fp[k * 25 + c] = M[c];
  }
  __syncthreads();

  // ---- Reduce partials: thread (q = ql, comps sp*3..sp*3+2) ----
  {
    const float* fp = (const float*)(sBuf + ql * ROWSTR);
#pragma unroll
    for (int j0 = 0; j0 < 3; ++j0) {
      int j = sp * 3 + j0;
      float s = fp[0 * 25 + j] + fp[1 * 25 + j] + fp[2 * 25 + j] +
                fp[3 * 25 + j];
      sM[ql * 25 + j] = s;
    }
  }
  __syncthreads();

  // ---- Epilogue phase 2 (all waves): out[q][w*3+m], lane w = ql ----
  float wreg[NBASIS];
#pragma unroll
  for (int v = 0; v < NBASIS; ++v) wreg[v] = Wmat[v * OUTM + ql];
  const float scale = 0.022097086912079608f;  // (1/sqrt(8)) / 16
#pragma unroll
  for (int i = 0; i < 8; ++i) {
    int q = sp * 8 + i;  // wave-uniform -> sM broadcasts
    const float* mq = sM + q * 25;
    float a0 = 0.f, a1 = 0.f, a2 = 0.f;
#pragma unroll
    for (int v = 0; v < NBASIS; ++v) {
      a0 = fmaf(wreg[v], mq[v * 3 + 0], a0);
      a1 = fmaf(wreg[v], mq[v * 3 + 1], a1);
      a2 = fmaf(wreg[v], mq[v * 3 + 2], a2);
    }
    size_t o = (size_t)(base + qg * QPB + q) * (OUTM * 3) + ql * 3;
    out[o + 0] = a0 * scale;
    out[o + 1] = a1 * scale;
    out[o + 2] = a2 * scale;
  }
}

// coords [B*N][3] -> x/y/z planes + float4 array.
__global__ void prep_kernel(const float* __restrict__ coords,
                            float* __restrict__ Xp, float* __restrict__ Yp,
                            float* __restrict__ Zp, float4* __restrict__ cpad) {
  int i = blockIdx.x * 256 + threadIdx.x;
  if (i < NQTOT) {
    float x = coords[3 * i + 0];
    float y = coords[3 * i + 1];
    float z = coords[3 * i + 2];
    Xp[i] = x; Yp[i] = y; Zp[i] = z;
    cpad[i] = make_float4(x, y, z, 0.f);
  }
}

extern "C" void kernel_launch(void* const* d_in, const int* in_sizes, int n_in,
                              void* d_out, int out_size, void* d_ws, size_t ws_size,
                              hipStream_t stream) {
  const float* coords = (const float*)d_in[0];
  const float* Wmat = (const float*)d_in[1];
  float* out = (float*)d_out;

  char* w = (char*)d_ws;
  float* Xp = (float*)(w);               // 128 KB
  float* Yp = (float*)(w + 131072);
  float* Zp = (float*)(w + 262144);
  float4* cpad = (float4*)(w + 393216);  // 512 KB

  prep_kernel<<<dim3((NQTOT + 255) / 256), dim3(256), 0, stream>>>(coords, Xp, Yp, Zp, cpad);
  se3_kernel<<<dim3(NBATCH, NPTS / QPB), dim3(TKNN), 0, stream>>>(Xp, Yp, Zp, cpad, Wmat, out);
}

// Round 5
// 170.583 us; speedup vs baseline: 1.1161x; 1.0241x over previous
//
#include <hip/hip_runtime.h>

typedef unsigned int u32;
typedef unsigned long long u64;
typedef float v2f __attribute__((ext_vector_type(2)));

#define NBATCH 8
#define NPTS   4096
#define NQTOT  (NBATCH * NPTS)   /* 32768 */
#define KNN    16
#define NBASIS 8
#define OUTM   64
#define NSPLIT 8
#define WIN    (NPTS / NSPLIT)   /* 512 candidates per window */
#define QPB    64
#define TKNN   (QPB * NSPLIT)    /* 512 threads = 8 waves */
#define GRP    8
#define ECAP   64                /* group-entry cap per phase (expected ~16) */
/* per-query LDS row: 64 funnel slots + 16 t16 slots + 1 pad (odd stride) */
#define ROWSTR 81
#define TOFF   64

// sentinel: d2 = +inf, idx = all-ones (sorts last)
#define SENT 0x7f800000ffffffffull

__device__ __forceinline__ void ce(u64& x, u64& y) {
  u64 a = x, b = y;
  bool sw = b < a;
  x = sw ? b : a;
  y = sw ? a : b;
}

// Batcher odd-even mergesort network (fully unrolled).
template <int N>
__device__ __forceinline__ void oems_sort(u64* a) {
#pragma unroll
  for (int p = 1; p < N; p <<= 1) {
#pragma unroll
    for (int k = p; k >= 1; k >>= 1) {
#pragma unroll
      for (int j = k & (p - 1); j + k < N; j += 2 * k) {
#pragma unroll
        for (int i = 0; i < k; ++i) {
          int lo = i + j, hi = i + j + k;
          if (hi < N && (lo / (2 * p)) == (hi / (2 * p)))
            ce(a[lo], a[hi]);
        }
      }
    }
  }
}

// t, a sorted asc -> t = smallest 16 of union, sorted asc.
__device__ __forceinline__ void merge16(u64 t[16], const u64 a[16]) {
  u64 m[16];
#pragma unroll
  for (int i = 0; i < 16; ++i) {
    u64 x = t[i], y = a[15 - i];
    m[i] = (x < y) ? x : y;
  }
#pragma unroll
  for (int k = 8; k >= 1; k >>= 1) {
#pragma unroll
    for (int i = 0; i < 16; ++i) {
      if ((i & k) == 0) ce(m[i], m[i | k]);
    }
  }
#pragma unroll
  for (int i = 0; i < 16; ++i) t[i] = m[i];
}

// Bit-exact d2 pair: ((dx^2+dy^2)+dz^2), no FMA contraction. v_pk ops round
// IEEE-identically to scalar (verified bit-exact vs reference rounds 0-3).
__device__ __forceinline__ v2f d2pair(v2f cx, v2f cy, v2f cz, v2f qx, v2f qy,
                                      v2f qz) {
#pragma clang fp contract(off)
  v2f dx = cx - qx;
  v2f dy = cy - qy;
  v2f dz = cz - qz;
  v2f d2 = (dx * dx + dy * dy) + dz * dz;
  return d2;
}

// Scalar bit-exact d2 (identical rounding to d2pair) — digest recompute.
// Proven bit-exact vs reference in round 1 (passed with this exact path).
__device__ __forceinline__ float d2s(float cx, float cy, float cz, float qx,
                                     float qy, float qz) {
#pragma clang fp contract(off)
  float dx = cx - qx;
  float dy = cy - qy;
  float dz = cz - qz;
  return (dx * dx + dy * dy) + dz * dz;
}

// Fused kNN + tensor-product features — R3 structure (synchronous rotating
// digest, proven correct) + group-encoded insertions. Scan stores ONE u32
// group-entry (want<<12 | candbase) per group with any hit — was an
// 8-iteration masked u64 store loop (~80 issues/group, the dominant VALU
// term per R3 post-mortem). The rotating digest wave expands entries
// STRICTLY BETWEEN BARRIERS (no concurrency — R4's concurrent digest wave
// failed correctness and is retired): decode bits -> gather cpad ->
// bit-exact scalar d2 recompute -> sort/merge into running top-16. thr is
// static during each scan phase, exactly as R3. Selection bit-identical.
// NO __launch_bounds__ min-waves (forced VGPR -> scratch spills, measured).
__global__ __launch_bounds__(TKNN) void se3_kernel(
    const float* __restrict__ Xp, const float* __restrict__ Yp,
    const float* __restrict__ Zp, const float4* __restrict__ cpad,
    const float* __restrict__ Wmat, float* __restrict__ out) {
  __shared__ u64 sBuf[QPB * ROWSTR];  // 41.5 KB: funnel + t16 per query row
  __shared__ u32 sCnt[QPB];
  __shared__ float sThr[QPB];
  __shared__ float sM[QPB * 25];      // reduced M[8][3], stride 25

  const int b = blockIdx.x;
  const int qg = blockIdx.y;
  const int tid = threadIdx.x;
  const int ql = tid & 63;
  const int sp = tid >> 6;  // window id, wave-uniform
  const int qi = qg * QPB + ql;
  const int base = b * NPTS;

  if (tid < QPB) sCnt[tid] = 0;

  // per-lane query coords (coalesced)
  const float qx = Xp[base + qi];
  const float qy = Yp[base + qi];
  const float qz = Zp[base + qi];
  const v2f qxx = {qx, qx}, qyy = {qy, qy}, qzz = {qz, qz};

  // wave-uniform candidate window -> scalar loads feeding packed math
  const int wbase = __builtin_amdgcn_readfirstlane(sp * WIN);
  const v2f* xs2 = (const v2f*)(Xp + base + wbase);
  const v2f* ys2 = (const v2f*)(Yp + base + wbase);
  const v2f* zs2 = (const v2f*)(Zp + base + wbase);
  const int sj = qi - wbase;  // self position inside window (may be OOR)

  u64* row = sBuf + (size_t)ql * ROWSTR;

  // ---- Seed: every thread sorts its window's first 16 candidates ----
  {
    u64 s16[16];
    float cd[16];
#pragma unroll
    for (int p = 0; p < 8; ++p) {
      v2f d2 = d2pair(xs2[p], ys2[p], zs2[p], qxx, qyy, qzz);
      cd[2 * p + 0] = d2.x;
      cd[2 * p + 1] = d2.y;
    }
#pragma unroll
    for (int i = 0; i < 16; ++i) {
      u64 v = ((u64)__float_as_uint(cd[i]) << 32) | (u32)(wbase + i);
      s16[i] = (i == sj) ? SENT : v;
    }
    oems_sort<16>(s16);

    // Round A: waves 1..4 publish pre-sorted lists into funnel slots.
    if (sp >= 1 && sp <= 4) {
#pragma unroll
      for (int e = 0; e < 16; ++e) row[(sp - 1) * 16 + e] = s16[e];
    }
    __syncthreads();
    if (sp == 0) {
      u64 t16[16];
#pragma unroll
      for (int e = 0; e < 16; ++e) t16[e] = s16[e];
#pragma unroll
      for (int s = 0; s < 4; ++s) {
        u64 a[16];
#pragma unroll
        for (int e = 0; e < 16; ++e) a[e] = row[s * 16 + e];
        merge16(t16, a);
      }
      // stash partial in sT while round B publishes
#pragma unroll
      for (int e = 0; e < 16; ++e) row[TOFF + e] = t16[e];
    }
    __syncthreads();
    // Round B: waves 5..7 publish.
    if (sp >= 5) {
#pragma unroll
      for (int e = 0; e < 16; ++e) row[(sp - 5) * 16 + e] = s16[e];
    }
    __syncthreads();
    if (sp == 0) {
      u64 t16[16];
#pragma unroll
      for (int e = 0; e < 16; ++e) t16[e] = row[TOFF + e];
#pragma unroll
      for (int s = 0; s < 3; ++s) {
        u64 a[16];
#pragma unroll
        for (int e = 0; e < 16; ++e) a[e] = row[s * 16 + e];
        merge16(t16, a);
      }
#pragma unroll
      for (int e = 0; e < 16; ++e) row[TOFF + e] = t16[e];
      sThr[ql] = __uint_as_float((u32)(t16[15] >> 32));
    }
    __syncthreads();
  }
  float thr = sThr[ql];

  // self-exclusion mask precompute (avoids per-candidate j!=qi compare)
  const int selfgrp = (sj >= 0 && sj < WIN) ? (sj >> 3) : -1;
  const u32 selfbit = 1u << (sj & 7);

  // entry buffer: u32 slots [0,64) of the row = u64 slots [0,32); dead
  // region outside scan+digest (funnel done; epilogue scratch comes later).
  u32* ebuf = (u32*)row;

  // ---- Main scan: doubling phases; digest wave rotates (1..5) ----
#pragma unroll
  for (int ph = 0; ph < 5; ++ph) {
    const int cstart = 16 << ph;  // [16,32),[32,64),...,[256,512)
    const int cend = 32 << ph;
#pragma unroll 2
    for (int g = cstart; g < cend; g += GRP) {
      v2f d2p[4];
#pragma unroll
      for (int p = 0; p < 4; ++p)
        d2p[p] = d2pair(xs2[(g >> 1) + p], ys2[(g >> 1) + p],
                        zs2[(g >> 1) + p], qxx, qyy, qzz);
      u32 want = 0;
#pragma unroll
      for (int i = 0; i < GRP; ++i)
        want |= (d2p[i >> 1][i & 1] <= thr) ? (1u << i) : 0u;
      if ((g >> 3) == selfgrp) want &= ~selfbit;
      if (want) {  // ONE u32 entry per group with any hit
        u32 slot = atomicAdd(&sCnt[ql], 1u);
        if (slot < ECAP) ebuf[slot] = (want << 12) | (u32)(wbase + g);
      }
    }
    __syncthreads();
    if (sp == ph + 1) {  // rotating digest wave (1..5), between barriers
      int n = (int)sCnt[ql];
      n = n < ECAP ? n : ECAP;
      if (__any(n > 0)) {
        u64 t16[16];
#pragma unroll
        for (int e = 0; e < 16; ++e) t16[e] = row[TOFF + e];
        int cursor = 0;
        u32 curWant = 0, curBase = 0;
        while (__any(cursor < n || curWant != 0)) {
          // pass 1: decode up to 16 candidate indices (VALU only)
          u32 kidx[16];
          u32 vmask = 0;
#pragma unroll
          for (int e = 0; e < 16; ++e) {
            if (curWant == 0 && cursor < n) {
              u32 ent = ebuf[cursor++];
              curWant = ent >> 12;
              curBase = ent & 0xFFFu;
            }
            if (curWant) {
              int bit = __ffs(curWant) - 1;
              curWant &= curWant - 1;
              kidx[e] = curBase + (u32)bit;
              vmask |= (1u << e);
            } else {
              kidx[e] = 0;
            }
          }
          // pass 2: batched gathers + bit-exact d2 recompute
          u64 a[16];
#pragma unroll
          for (int e = 0; e < 16; ++e) {
            float4 c = cpad[base + (int)kidx[e]];
            float d2 = d2s(c.x, c.y, c.z, qx, qy, qz);
            u64 key = ((u64)__float_as_uint(d2) << 32) | kidx[e];
            a[e] = (vmask & (1u << e)) ? key : SENT;
          }
          oems_sort<16>(a);
          merge16(t16, a);
        }
#pragma unroll
        for (int e = 0; e < 16; ++e) row[TOFF + e] = t16[e];
        sThr[ql] = __uint_as_float((u32)(t16[15] >> 32));
      }
      sCnt[ql] = 0;
    }
    __syncthreads();
    thr = sThr[ql];
  }

  // ---- Epilogue phase 1 (waves 0-3): partial M over 4 neighbors each ----
  // Thread (q = tid&63, quarter k = sp) -> partials into dead funnel
  // floats [k*25, k*25+24) of row q (< float offset 100; t16 at 128+).
  if (sp < 4) {
    const int k = sp;
    u64 pv[4];
#pragma unroll
    for (int e = 0; e < 4; ++e) pv[e] = row[TOFF + k * 4 + e];
    float4 nc[4];
    float dd[4];
#pragma unroll
    for (int e = 0; e < 4; ++e) {
      nc[e] = cpad[base + (int)(u32)pv[e]];  // independent gathers
      dd[e] = __uint_as_float((u32)(pv[e] >> 32));
    }
    float M[24];
#pragma unroll
    for (int j = 0; j < 24; ++j) M[j] = 0.f;
#pragma unroll
    for (int e = 0; e < 4; ++e) {
      float rx = nc[e].x - qx;  // sender - receiver
      float ry = nc[e].y - qy;
      float rz = nc[e].z - qz;
      float dist = sqrtf(dd[e]);
      float inv = 1.0f / (dist + 1e-8f);
      rx *= inv; ry *= inv; rz *= inv;
      float cut = fminf(dist * 0.1f, 1.0f);
      float g[NBASIS], s = 0.f;
#pragma unroll
      for (int v = 0; v < NBASIS; ++v) {
        float t = cut - (float)v * (1.0f / 7.0f);
        g[v] = __expf(-32.0f * t * t);  // sigma = 1/8 -> 1/(2s^2) = 32
        s += g[v];
      }
      float rs = 1.0f / s;
#pragma unroll
      for (int v = 0; v < NBASIS; ++v) {
        float rb = g[v] * rs;
        M[v * 3 + 0] = fmaf(rb, rx, M[v * 3 + 0]);
        M[v * 3 + 1] = fmaf(rb, ry, M[v * 3 + 1]);
        M[v * 3 + 2] = fmaf(rb, rz, M[v * 3 + 2]);
      }
    }
    float* fp = (float*)row;
#pragma unroll
    for (int c = 0; c < 24; ++c) fp[k * 25 + c] = M[c];
  }
  __syncthreads();

  // ---- Reduce partials: thread (q = ql, comps sp*3..sp*3+2) ----
  {
    const float* fp = (const float*)row;
#pragma unroll
    for (int j0 = 0; j0 < 3; ++j0) {
      int j = sp * 3 + j0;
      float s = fp[0 * 25 + j] + fp[1 * 25 + j] + fp[2 * 25 + j] +
                fp[3 * 25 + j];
      sM[ql * 25 + j] = s;
    }
  }
  __syncthreads();

  // ---- Epilogue phase 2 (all waves): out[q][w*3+m], lane w = ql ----
  float wreg[NBASIS];
#pragma unroll
  for (int v = 0; v < NBASIS; ++v) wreg[v] = Wmat[v * OUTM + ql];
  const float scale = 0.022097086912079608f;  // (1/sqrt(8)) / 16
#pragma unroll
  for (int i = 0; i < 8; ++i) {
    int q = sp * 8 + i;  // wave-uniform -> sM broadcasts
    const float* mq = sM + q * 25;
    float a0 = 0.f, a1 = 0.f, a2 = 0.f;
#pragma unroll
    for (int v = 0; v < NBASIS; ++v) {
      a0 = fmaf(wreg[v], mq[v * 3 + 0], a0);
      a1 = fmaf(wreg[v], mq[v * 3 + 1], a1);
      a2 = fmaf(wreg[v], mq[v * 3 + 2], a2);
    }
    size_t o = (size_t)(base + qg * QPB + q) * (OUTM * 3) + ql * 3;
    out[o + 0] = a0 * scale;
    out[o + 1] = a1 * scale;
    out[o + 2] = a2 * scale;
  }
}

// coords [B*N][3] -> x/y/z planes + float4 array.
__global__ void prep_kernel(const float* __restrict__ coords,
                            float* __restrict__ Xp, float* __restrict__ Yp,
                            float* __restrict__ Zp, float4* __restrict__ cpad) {
  int i = blockIdx.x * 256 + threadIdx.x;
  if (i < NQTOT) {
    float x = coords[3 * i + 0];
    float y = coords[3 * i + 1];
    float z = coords[3 * i + 2];
    Xp[i] = x; Yp[i] = y; Zp[i] = z;
    cpad[i] = make_float4(x, y, z, 0.f);
  }
}

extern "C" void kernel_launch(void* const* d_in, const int* in_sizes, int n_in,
                              void* d_out, int out_size, void* d_ws, size_t ws_size,
                              hipStream_t stream) {
  const float* coords = (const float*)d_in[0];
  const float* Wmat = (const float*)d_in[1];
  float* out = (float*)d_out;

  char* w = (char*)d_ws;
  float* Xp = (float*)(w);               // 128 KB
  float* Yp = (float*)(w + 131072);
  float* Zp = (float*)(w + 262144);
  float4* cpad = (float4*)(w + 393216);  // 512 KB

  prep_kernel<<<dim3((NQTOT + 255) / 256), dim3(256), 0, stream>>>(coords, Xp, Yp, Zp, cpad);
  se3_kernel<<<dim3(NBATCH, NPTS / QPB), dim3(TKNN), 0, stream>>>(Xp, Yp, Zp, cpad, Wmat, out);
}